// Round 11
// baseline (60.647 us; speedup 1.0000x reference)
//
#include <hip/hip_runtime.h>

namespace {
constexpr int       N_ELEMS = 262144;
constexpr long long N_NODES = 263169;
constexpr int BLK     = 256;
constexpr int EPB     = 64;                    // elements per tile
constexpr int TILES   = N_ELEMS / EPB;         // 4096
constexpr int PBLOCKS = 1024;                  // persistent blocks, 4/CU
constexpr int TPB     = TILES / PBLOCKS;       // 4 tiles per block (contiguous)
constexpr int CBLOCKS = 1024;                  // calibration blocks
constexpr long long B_F4 = (long long)N_ELEMS * 24;   // 6291456 float4s in B

// folded material constants (fp32, match reference math)
constexpr float GC_2L0  = 0.09f;
constexpr float L0SQ    = 0.015f * 0.015f;
constexpr float MU_     = 80.76923076923077f;
constexpr float K_MOD   = 175.0f;
constexpr float PENALTY = 1799.82f;
}

typedef float vfloat4 __attribute__((ext_vector_type(4)));

__device__ __forceinline__ float waveReduce(float x) {
#pragma unroll
    for (int off = 32; off; off >>= 1) x += __shfl_down(x, off, 64);
    return x;
}

__global__ __launch_bounds__(256) void fused_energy(
    const float* __restrict__ u, const float* __restrict__ v,
    const float* __restrict__ c, const float* __restrict__ prev_c,
    const int* __restrict__ conn,
    const float* __restrict__ Nf, const float* __restrict__ dNdx,
    const float* __restrict__ B, const float* __restrict__ vol,
    float* __restrict__ partials)
{
    __shared__ vfloat4 ldsB[24 * 65];    // [f4row][elem] transposed B tile
    __shared__ vfloat4 ldsD[2 * 257];    // [f4row][unit] transposed dNdx tile

    const int k = threadIdx.x;
    const int tile0 = blockIdx.x * TPB;
    const vfloat4* Bf4 = reinterpret_cast<const vfloat4*>(B);
    const vfloat4* Df4 = reinterpret_cast<const vfloat4*>(dNdx);
    const vfloat4* Nf4 = reinterpret_cast<const vfloat4*>(Nf);

    // ---- nodal irreversibility term (grid-stride) ------------------------
    float Eirr = 0.f;
    for (long long n = (long long)blockIdx.x * BLK + k; n < N_NODES;
         n += (long long)PBLOCKS * BLK) {
        const float d = fmaxf(prev_c[n] - c[n], 0.f);
        Eirr += 0.5f * PENALTY * d * d;
    }

    // staging registers (single set for LDS-bound data; ping-pong for
    // register-resident per-unit data consumed at compute time)
    int sCn;
    vfloat4 sB0, sB1, sB2, sB3, sB4, sB5, sD0, sD1;
    vfloat4 sN[2];  float sVol[2];
    float gC[2], gU[2], gV[2];
    float Eel = 0.f, Efr = 0.f;

    const int m = k >> 2, ip = k & 3, base = k & ~3;

    auto compute = [&](int s) {
        // redistribute gathered nodal values within the 4-lane element group
        const float c0 = __shfl(gC[s], base),     c1 = __shfl(gC[s], base + 1);
        const float c2 = __shfl(gC[s], base + 2), c3 = __shfl(gC[s], base + 3);
        const float u0 = __shfl(gU[s], base),     u1 = __shfl(gU[s], base + 1);
        const float u2 = __shfl(gU[s], base + 2), u3 = __shfl(gU[s], base + 3);
        const float v0 = __shfl(gV[s], base),     v1 = __shfl(gV[s], base + 1);
        const float v2 = __shfl(gV[s], base + 2), v3 = __shfl(gV[s], base + 3);

        const vfloat4 Nr = sN[s];
        const float  vip = sVol[s];
        const vfloat4 dx = ldsD[k], dy = ldsD[257 + k];
        const vfloat4 b0 = ldsB[(6 * ip + 0) * 65 + m];
        const vfloat4 b1 = ldsB[(6 * ip + 1) * 65 + m];
        const vfloat4 b2 = ldsB[(6 * ip + 2) * 65 + m];
        const vfloat4 b3 = ldsB[(6 * ip + 3) * 65 + m];
        const vfloat4 b4 = ldsB[(6 * ip + 4) * 65 + m];
        const vfloat4 b5 = ldsB[(6 * ip + 5) * 65 + m];

        const float o0 = 1.f - c0, o1 = 1.f - c1, o2 = 1.f - c2, o3 = 1.f - c3;
        const float omc = Nr.x * o0 + Nr.y * o1 + Nr.z * o2 + Nr.w * o3;
        const float g   = omc * omc;
        const float cip = 1.f - omc;
        const float gx  = dx.x * c0 + dx.y * c1 + dx.z * c2 + dx.w * c3;
        const float gy  = dy.x * c0 + dy.y * c1 + dy.z * c2 + dy.w * c3;
        Efr += GC_2L0 * (cip * cip + L0SQ * (gx * gx + gy * gy)) * vip;

        const float exx = b0.x * u0 + b0.y * v0 + b0.z * u1 + b0.w * v1
                        + b1.x * u2 + b1.y * v2 + b1.z * u3 + b1.w * v3;
        const float eyy = b2.x * u0 + b2.y * v0 + b2.z * u1 + b2.w * v1
                        + b3.x * u2 + b3.y * v2 + b3.z * u3 + b3.w * v3;
        const float gxy = b4.x * u0 + b4.y * v0 + b4.z * u1 + b4.w * v1
                        + b5.x * u2 + b5.y * v2 + b5.z * u3 + b5.w * v3;
        const float exy = 0.5f * gxy;
        const float tr  = exx + eyy, tr3 = tr * (1.f / 3.f);
        const float dxx = exx - tr3, dyy = eyy - tr3, dzz = -tr3;
        const float dev2 = dxx * dxx + dyy * dyy + dzz * dzz + 2.f * exy * exy;
        const float trp = fmaxf(tr, 0.f), trn = fminf(tr, 0.f);
        Eel += ((0.5f * K_MOD * trp * trp + MU_ * dev2) * g
                + 0.5f * K_MOD * trn * trn) * vip;
    };

    // ---- prologue: fully stage tile0 -------------------------------------
    {
        const long long tt = tile0;
        sCn = conn[tt * 256 + k];                       // conn first (oldest)
        sB0 = Bf4[tt * 1536 + k       ]; sB1 = Bf4[tt * 1536 + k +  256];
        sB2 = Bf4[tt * 1536 + k +  512]; sB3 = Bf4[tt * 1536 + k +  768];
        sB4 = Bf4[tt * 1536 + k + 1024]; sB5 = Bf4[tt * 1536 + k + 1280];
        sD0 = Df4[tt * 512 + k]; sD1 = Df4[tt * 512 + k + 256];
        sN[0]   = Nf4[tt * 256 + k];
        sVol[0] = vol[tt * 256 + k];
        gC[0] = c[sCn]; gU[0] = u[sCn]; gV[0] = v[sCn];
        { int j = k;        ldsB[(j % 24) * 65 + j / 24] = sB0; }
        { int j = k +  256; ldsB[(j % 24) * 65 + j / 24] = sB1; }
        { int j = k +  512; ldsB[(j % 24) * 65 + j / 24] = sB2; }
        { int j = k +  768; ldsB[(j % 24) * 65 + j / 24] = sB3; }
        { int j = k + 1024; ldsB[(j % 24) * 65 + j / 24] = sB4; }
        { int j = k + 1280; ldsB[(j % 24) * 65 + j / 24] = sB5; }
        ldsD[(k & 1) * 257 + (k >> 1)] = sD0;
        { int j = k + 256;  ldsD[(j & 1) * 257 + (j >> 1)] = sD1; }
        __syncthreads();
    }

    // ---- pipelined main loop ---------------------------------------------
#pragma unroll
    for (int t = 0; t < TPB; ++t) {
        const int cur = t & 1, nxt = cur ^ 1;
        const bool more = (t + 1 < TPB);
        if (more) {   // issue next tile's loads, conn first
            const long long tt = tile0 + t + 1;
            sCn = conn[tt * 256 + k];
            sB0 = Bf4[tt * 1536 + k       ]; sB1 = Bf4[tt * 1536 + k +  256];
            sB2 = Bf4[tt * 1536 + k +  512]; sB3 = Bf4[tt * 1536 + k +  768];
            sB4 = Bf4[tt * 1536 + k + 1024]; sB5 = Bf4[tt * 1536 + k + 1280];
            sD0 = Df4[tt * 512 + k]; sD1 = Df4[tt * 512 + k + 256];
            sN[nxt]   = Nf4[tt * 256 + k];
            sVol[nxt] = vol[tt * 256 + k];
        }
        compute(cur);                 // hides the in-flight loads
        if (more) {                   // gathers: wait only on conn (oldest)
            gC[nxt] = c[sCn]; gU[nxt] = u[sCn]; gV[nxt] = v[sCn];
        }
        __syncthreads();
        if (more) {                   // commit next tile into LDS
            { int j = k;        ldsB[(j % 24) * 65 + j / 24] = sB0; }
            { int j = k +  256; ldsB[(j % 24) * 65 + j / 24] = sB1; }
            { int j = k +  512; ldsB[(j % 24) * 65 + j / 24] = sB2; }
            { int j = k +  768; ldsB[(j % 24) * 65 + j / 24] = sB3; }
            { int j = k + 1024; ldsB[(j % 24) * 65 + j / 24] = sB4; }
            { int j = k + 1280; ldsB[(j % 24) * 65 + j / 24] = sB5; }
            ldsD[(k & 1) * 257 + (k >> 1)] = sD0;
            { int j = k + 256;  ldsD[(j & 1) * 257 + (j >> 1)] = sD1; }
            __syncthreads();
        }
    }

    // ---- block reduction -> contention-free partial store ----------------
    Eel  = waveReduce(Eel);
    Efr  = waveReduce(Efr);
    Eirr = waveReduce(Eirr);
    __shared__ float sE[4], sF[4], sI[4];
    const int lane = k & 63, wid = k >> 6;
    if (lane == 0) { sE[wid] = Eel; sF[wid] = Efr; sI[wid] = Eirr; }
    __syncthreads();
    if (k == 0) {
        float* p = partials + 3ll * blockIdx.x;
        p[0] = sE[0] + sE[1] + sE[2] + sE[3];
        p[1] = sF[0] + sF[1] + sF[2] + sF[3];
        p[2] = sI[0] + sI[1] + sI[2] + sI[3];
    }
}

__global__ __launch_bounds__(256) void final_reduce(
    const float* __restrict__ partials, float* __restrict__ out)
{
    float s0 = 0.f, s1 = 0.f, s2 = 0.f;
    for (int i = threadIdx.x; i < PBLOCKS; i += 256) {
        const float* p = partials + 3ll * i;
        s0 += p[0]; s1 += p[1]; s2 += p[2];
    }
    s0 = waveReduce(s0);
    s1 = waveReduce(s1);
    s2 = waveReduce(s2);
    __shared__ float sA[4], sB[4], sC[4];
    const int lane = threadIdx.x & 63, wid = threadIdx.x >> 6;
    if (lane == 0) { sA[wid] = s0; sB[wid] = s1; sC[wid] = s2; }
    __syncthreads();
    if (threadIdx.x == 0) {
        out[0] = sA[0] + sA[1] + sA[2] + sA[3];
        out[1] = sB[0] + sB[1] + sB[2] + sB[3];
        out[2] = sC[0] + sC[1] + sC[2] + sC[3];
    }
}

// In-harness bandwidth reference: textbook grid-stride float4 read-reduce
// over B (100.7 MB). Result stored to an unused ws region (never read).
__global__ __launch_bounds__(256) void calib_stream(
    const float* __restrict__ B, float* __restrict__ sink)
{
    const long long gtid = (long long)blockIdx.x * BLK + threadIdx.x;
    const vfloat4* p = reinterpret_cast<const vfloat4*>(B);
    vfloat4 acc = {0.f, 0.f, 0.f, 0.f};
    for (long long i = gtid; i < B_F4; i += (long long)CBLOCKS * BLK)
        acc += p[i];
    float s = acc.x + acc.y + acc.z + acc.w;
    s = waveReduce(s);
    __shared__ float sW[4];
    const int lane = threadIdx.x & 63, wid = threadIdx.x >> 6;
    if (lane == 0) sW[wid] = s;
    __syncthreads();
    if (threadIdx.x == 0) sink[blockIdx.x] = sW[0] + sW[1] + sW[2] + sW[3];
}

extern "C" void kernel_launch(void* const* d_in, const int* in_sizes, int n_in,
                              void* d_out, int out_size, void* d_ws, size_t ws_size,
                              hipStream_t stream) {
    const float* u      = (const float*)d_in[0];
    const float* v      = (const float*)d_in[1];
    const float* c      = (const float*)d_in[2];
    const float* prev_c = (const float*)d_in[3];
    const int*   conn   = (const int*)d_in[4];
    const float* Nf     = (const float*)d_in[5];
    const float* dNdx   = (const float*)d_in[6];
    const float* B      = (const float*)d_in[7];
    const float* vol    = (const float*)d_in[8];
    float* out      = (float*)d_out;
    float* partials = (float*)d_ws;                  // 1024*3 floats
    float* sink     = partials + 3 * PBLOCKS;        // 1024 floats, unused by reduce

    fused_energy<<<PBLOCKS, BLK, 0, stream>>>(
        u, v, c, prev_c, conn, Nf, dNdx, B, vol, partials);
    final_reduce<<<1, BLK, 0, stream>>>(partials, out);
    calib_stream<<<CBLOCKS, BLK, 0, stream>>>(B, sink);
}

// Round 12
// 50.477 us; speedup vs baseline: 1.2015x; 1.2015x over previous
//
#include <hip/hip_runtime.h>

namespace {
constexpr int N_ELEMS  = 262144;
constexpr int N_NODES  = 263169;
constexpr int BLK      = 256;
constexpr int EPB      = 64;                  // elements per block
constexpr int NBLOCKS  = N_ELEMS / EPB;       // 4096
constexpr int PACK_BLOCKS = (N_NODES + BLK - 1) / BLK;   // 1029

// ws layout (floats): [0, WS2_F) = packed nodes (f4); then partials
constexpr long long WS2_F4   = 263232;        // N_NODES rounded up to 64
constexpr long long P_EL_OFF = WS2_F4 * 4;            // 4096*2 floats
constexpr long long P_IR_OFF = P_EL_OFF + 2LL * NBLOCKS;  // 1029 floats

// folded material constants (fp32, match reference math)
constexpr float GC_2L0  = 0.09f;
constexpr float L0SQ    = 0.015f * 0.015f;
constexpr float MU_     = 80.76923076923077f;
constexpr float K_MOD   = 175.0f;
constexpr float PENALTY = 1799.82f;
}

typedef float vfloat4 __attribute__((ext_vector_type(4)));

__device__ __forceinline__ float waveReduce(float x) {
#pragma unroll
    for (int off = 32; off; off >>= 1) x += __shfl_down(x, off, 64);
    return x;
}

// ---------------------------------------------------------------------------
// Kernel 1: pack nodal fields {c,u,v} into one 16B record per node
// (lane-linear read + write), and compute the irreversibility penalty.
// ---------------------------------------------------------------------------
__global__ __launch_bounds__(256) void pack_nodes(
    const float* __restrict__ u, const float* __restrict__ v,
    const float* __restrict__ c, const float* __restrict__ prev_c,
    float* __restrict__ ws2, float* __restrict__ partialsI)
{
    const int i = blockIdx.x * BLK + threadIdx.x;
    float Eirr = 0.f;
    if (i < N_NODES) {
        const float ci = c[i], ui = u[i], vi = v[i];
        const float d = fmaxf(prev_c[i] - ci, 0.f);
        Eirr = 0.5f * PENALTY * d * d;
        vfloat4 r; r.x = ci; r.y = ui; r.z = vi; r.w = 0.f;
        __builtin_nontemporal_store(r, reinterpret_cast<vfloat4*>(ws2) + i);
    }
    Eirr = waveReduce(Eirr);
    __shared__ float sI[4];
    const int lane = threadIdx.x & 63, wid = threadIdx.x >> 6;
    if (lane == 0) sI[wid] = Eirr;
    __syncthreads();
    if (threadIdx.x == 0)
        partialsI[blockIdx.x] = sI[0] + sI[1] + sI[2] + sI[3];
}

// ---------------------------------------------------------------------------
// Kernel 2: energy. All global loads lane-linear except ONE f4 gather/thread.
// ---------------------------------------------------------------------------
__global__ __launch_bounds__(256) void fused_energy(
    const int* __restrict__ conn,
    const float* __restrict__ Nf, const float* __restrict__ dNdx,
    const float* __restrict__ B, const float* __restrict__ vol,
    const float* __restrict__ ws2, float* __restrict__ partials)
{
    __shared__ vfloat4 ldsB[24 * 65];    // [f4row][elem] transposed B tile
    __shared__ vfloat4 ldsD[2 * 257];    // [dxdy][unit] transposed dNdx tile

    const int k     = threadIdx.x;
    const int ebase = blockIdx.x * EPB;
    const vfloat4* Bf4 = reinterpret_cast<const vfloat4*>(B);
    const vfloat4* Df4 = reinterpret_cast<const vfloat4*>(dNdx);
    const vfloat4* Nf4 = reinterpret_cast<const vfloat4*>(Nf);
    const vfloat4* W4  = reinterpret_cast<const vfloat4*>(ws2);

    // ---- B staging: 1536 f4, pure unit-stride stream ---------------------
    const vfloat4* Bg = Bf4 + (long long)ebase * 24;
#pragma unroll
    for (int r = 0; r < 6; ++r) {
        const int j = k + BLK * r;
        ldsB[(j % 24) * 65 + (j / 24)] = Bg[j];
    }
    // ---- dNdx staging: 512 f4, pure unit-stride stream -------------------
    const vfloat4* Dg = Df4 + (long long)ebase * 8;
#pragma unroll
    for (int r = 0; r < 2; ++r) {
        const int j = k + BLK * r;
        ldsD[(j & 1) * 257 + (j >> 1)] = Dg[j];
    }

    // ---- THE gather: one f4 per thread (node (k&3) of element k>>2) ------
    const int idx = conn[4ll * ebase + k];       // lane-linear index load
    const vfloat4 nv = W4[idx];                  // single divergent load

    // ---- lane-linear per-unit loads --------------------------------------
    const vfloat4 Nr  = Nf4[4ll * ebase + k];
    const float   vip = vol[4ll * ebase + k];

    // ---- redistribute nodal values within the 4-lane element group -------
    const int base = k & ~3;
    const float c0 = __shfl(nv.x, base),     c1 = __shfl(nv.x, base + 1);
    const float c2 = __shfl(nv.x, base + 2), c3 = __shfl(nv.x, base + 3);
    const float u0 = __shfl(nv.y, base),     u1 = __shfl(nv.y, base + 1);
    const float u2 = __shfl(nv.y, base + 2), u3 = __shfl(nv.y, base + 3);
    const float v0 = __shfl(nv.z, base),     v1 = __shfl(nv.z, base + 1);
    const float v2 = __shfl(nv.z, base + 2), v3 = __shfl(nv.z, base + 3);

    __syncthreads();

    // ---- read this unit's B/dNdx from LDS --------------------------------
    const int m = k >> 2, ip = k & 3;
    const vfloat4 dx = ldsD[k], dy = ldsD[257 + k];
    const vfloat4 b0 = ldsB[(6 * ip + 0) * 65 + m];
    const vfloat4 b1 = ldsB[(6 * ip + 1) * 65 + m];
    const vfloat4 b2 = ldsB[(6 * ip + 2) * 65 + m];
    const vfloat4 b3 = ldsB[(6 * ip + 3) * 65 + m];
    const vfloat4 b4 = ldsB[(6 * ip + 4) * 65 + m];
    const vfloat4 b5 = ldsB[(6 * ip + 5) * 65 + m];

    // ---- compute one (e, ip) unit ----------------------------------------
    const float o0 = 1.f - c0, o1 = 1.f - c1, o2 = 1.f - c2, o3 = 1.f - c3;
    const float omc = Nr.x * o0 + Nr.y * o1 + Nr.z * o2 + Nr.w * o3;
    const float g   = omc * omc;
    const float cip = 1.f - omc;
    const float gx  = dx.x * c0 + dx.y * c1 + dx.z * c2 + dx.w * c3;
    const float gy  = dy.x * c0 + dy.y * c1 + dy.z * c2 + dy.w * c3;
    float Efr = GC_2L0 * (cip * cip + L0SQ * (gx * gx + gy * gy)) * vip;

    const float exx = b0.x * u0 + b0.y * v0 + b0.z * u1 + b0.w * v1
                    + b1.x * u2 + b1.y * v2 + b1.z * u3 + b1.w * v3;
    const float eyy = b2.x * u0 + b2.y * v0 + b2.z * u1 + b2.w * v1
                    + b3.x * u2 + b3.y * v2 + b3.z * u3 + b3.w * v3;
    const float gxy = b4.x * u0 + b4.y * v0 + b4.z * u1 + b4.w * v1
                    + b5.x * u2 + b5.y * v2 + b5.z * u3 + b5.w * v3;
    const float exy = 0.5f * gxy;
    const float tr  = exx + eyy, tr3 = tr * (1.f / 3.f);
    const float dxx = exx - tr3, dyy = eyy - tr3, dzz = -tr3;
    const float dev2 = dxx * dxx + dyy * dyy + dzz * dzz + 2.f * exy * exy;
    const float trp = fmaxf(tr, 0.f), trn = fminf(tr, 0.f);
    float Eel = ((0.5f * K_MOD * trp * trp + MU_ * dev2) * g
                 + 0.5f * K_MOD * trn * trn) * vip;

    // ---- block reduction -> contention-free partial store ----------------
    Eel = waveReduce(Eel);
    Efr = waveReduce(Efr);
    __shared__ float sE[4], sF[4];
    const int lane = k & 63, wid = k >> 6;
    if (lane == 0) { sE[wid] = Eel; sF[wid] = Efr; }
    __syncthreads();
    if (k == 0) {
        float* p = partials + 2ll * blockIdx.x;
        p[0] = sE[0] + sE[1] + sE[2] + sE[3];
        p[1] = sF[0] + sF[1] + sF[2] + sF[3];
    }
}

__global__ __launch_bounds__(256) void final_reduce(
    const float* __restrict__ partials, const float* __restrict__ partialsI,
    float* __restrict__ out)
{
    float s0 = 0.f, s1 = 0.f, s2 = 0.f;
    for (int i = threadIdx.x; i < NBLOCKS; i += 256) {
        s0 += partials[2ll * i];
        s1 += partials[2ll * i + 1];
    }
    for (int i = threadIdx.x; i < PACK_BLOCKS; i += 256)
        s2 += partialsI[i];
    s0 = waveReduce(s0);
    s1 = waveReduce(s1);
    s2 = waveReduce(s2);
    __shared__ float sA[4], sB[4], sC[4];
    const int lane = threadIdx.x & 63, wid = threadIdx.x >> 6;
    if (lane == 0) { sA[wid] = s0; sB[wid] = s1; sC[wid] = s2; }
    __syncthreads();
    if (threadIdx.x == 0) {
        out[0] = sA[0] + sA[1] + sA[2] + sA[3];
        out[1] = sB[0] + sB[1] + sB[2] + sB[3];
        out[2] = sC[0] + sC[1] + sC[2] + sC[3];
    }
}

extern "C" void kernel_launch(void* const* d_in, const int* in_sizes, int n_in,
                              void* d_out, int out_size, void* d_ws, size_t ws_size,
                              hipStream_t stream) {
    const float* u      = (const float*)d_in[0];
    const float* v      = (const float*)d_in[1];
    const float* c      = (const float*)d_in[2];
    const float* prev_c = (const float*)d_in[3];
    const int*   conn   = (const int*)d_in[4];
    const float* Nf     = (const float*)d_in[5];
    const float* dNdx   = (const float*)d_in[6];
    const float* B      = (const float*)d_in[7];
    const float* vol    = (const float*)d_in[8];
    float* out = (float*)d_out;

    float* ws2       = (float*)d_ws;              // 263232 f4 = 4.21 MB
    float* partials  = ws2 + P_EL_OFF;            // 4096*2 floats
    float* partialsI = ws2 + P_IR_OFF;            // 1029 floats

    pack_nodes<<<PACK_BLOCKS, BLK, 0, stream>>>(u, v, c, prev_c, ws2, partialsI);
    fused_energy<<<NBLOCKS, BLK, 0, stream>>>(conn, Nf, dNdx, B, vol, ws2, partials);
    final_reduce<<<1, BLK, 0, stream>>>(partials, partialsI, out);
}